// Round 15
// baseline (128.167 us; speedup 1.0000x reference)
//
#include <hip/hip_runtime.h>
#include <hip/hip_bf16.h>

#define N0 300000
#define N1 60000
#define N2 6000
#define E1 1200000
#define E2 300000
#define D 128
#define DO 64
#define HBUF 30000

#define WL_CAP 32768
#define UC_CAP 256
#define CAP 192               // per-dst edge bucket capacity (Poisson(50); max ~100)

#define CONV_BLKS 469         // x256 x4 chunks x8 elems >= 3.84M hist elems
#define ES_BLKS 4688          // x256 >= E1 (E2 scatter shares these blocks)
#define BFRAG_BLKS 160        // 40960 exactly

typedef __attribute__((ext_vector_type(8))) short bfrag8;
typedef __attribute__((ext_vector_type(4))) float f32x4;

__device__ __forceinline__ float bf2f(unsigned int u) {
    union { unsigned int i; float f; } c; c.i = u << 16; return c.f;
}
__device__ __forceinline__ unsigned short f2bf(float f) {
    return __bfloat16_as_ushort(__float2bfloat16(f));
}

// ---- 1. zero: mcount + padded degcnt + cnt + nuc ----
__global__ void k_zero(int* __restrict__ mcount, int* __restrict__ degcnt,
                       int* __restrict__ cnt, int* __restrict__ nuc) {
    int i = blockIdx.x * 256 + threadIdx.x;
    int stride = gridDim.x * 256;
    for (int j = i; j < HBUF; j += stride) mcount[j] = 0;
    for (int j = i; j < N2 * 16; j += stride) degcnt[j] = 0;
    if (i == 0) { *cnt = 0; *nuc = 0; }
}

// ---- 2. node scan: mcount histogram + uncached registration + remap build ----
__global__ void k_scan(const int* __restrict__ hmap, int* __restrict__ mcount,
                       int* __restrict__ nuc, int* __restrict__ uc_node,
                       int* __restrict__ remap) {
    int node = blockIdx.x * 256 + threadIdx.x;
    if (node >= N1) return;
    int m = hmap[node];
    if (m >= 0) {
        atomicAdd(&mcount[m], 1);
        remap[node] = m;
    } else {
        int slot = atomicAdd(nuc, 1);
        if (slot > UC_CAP - 1) slot = UC_CAP - 1;
        uc_node[slot] = node;
        remap[node] = HBUF + slot;
    }
}

// ---- 3. k_big: [0,469) hist->bf16 convert + fused weighted BN-stats partials;
//        [469,5157) E1 worklist scan + E2 scatter (remap'd payload, padded degcnt);
//        [5157,5317) B-fragment pack ----
__global__ void __launch_bounds__(256) k_big(
        const float* __restrict__ hist, unsigned short* __restrict__ histbf,
        const int* __restrict__ mcount, float* __restrict__ psum,
        const int* __restrict__ hmap, const int* __restrict__ remap,
        const int* __restrict__ dst1, int* __restrict__ cnt, int* __restrict__ list,
        const int* __restrict__ src2, const int* __restrict__ dst2,
        const int* __restrict__ et2, int* __restrict__ degcnt,
        int* __restrict__ epay,
        const float* __restrict__ W2, const float* __restrict__ Wself2,
        unsigned short* __restrict__ BF) {
    int b = blockIdx.x, tid = threadIdx.x;
    if (b < CONV_BLKS) {
        __shared__ float ls1[2048], ls2[2048];
        float s[8] = {0,0,0,0,0,0,0,0}, ss[8] = {0,0,0,0,0,0,0,0};
        const float4* h4 = (const float4*)hist;
#pragma unroll
        for (int it = 0; it < 4; it++) {
            int i = (b * 4 + it) * 256 + tid;      // thread-chunk of 8 elems
            if (i >= 480000) break;                // 3.84M/8
            int row = i >> 4;                      // 16 chunks per row
            float w = (float)mcount[row];
            float4 u = h4[(size_t)i * 2], v = h4[(size_t)i * 2 + 1];
            float e[8] = {u.x, u.y, u.z, u.w, v.x, v.y, v.z, v.w};
            union { unsigned short q[8]; uint4 o; } o;
#pragma unroll
            for (int j = 0; j < 8; j++) {
                o.q[j] = f2bf(e[j]);
                s[j] += w * e[j];
                ss[j] += w * e[j] * e[j];
            }
            *(uint4*)(histbf + (size_t)i * 8) = o.o;
        }
#pragma unroll
        for (int j = 0; j < 8; j++) { ls1[tid * 8 + j] = s[j]; ls2[tid * 8 + j] = ss[j]; }
        __syncthreads();
        if (tid < 128) {
            int qq = tid >> 3, jj = tid & 7;       // col c = qq*8+jj = tid
            float S = 0.f, SS = 0.f;
#pragma unroll
            for (int g = 0; g < 16; g++) {
                int src = (qq + 16 * g) * 8 + jj;
                S += ls1[src]; SS += ls2[src];
            }
            psum[b * 256 + tid] = S;
            psum[b * 256 + 128 + tid] = SS;
        }
    } else if (b < CONV_BLKS + ES_BLKS) {
        int e = (b - CONV_BLKS) * 256 + tid;
        if (e < E2) {
            int d = dst2[e];
            int pos = atomicAdd(&degcnt[d * 16], 1);   // 1 counter / 64B line
            if (pos < CAP) epay[d * CAP + pos] = remap[src2[e]] | (et2[e] << 16);
        }
        if (e < E1 && hmap[dst1[e]] < 0) {
            int i = atomicAdd(cnt, 1);
            if (i < WL_CAP) list[i] = e;
        }
    } else {
        int idx = (b - CONV_BLKS - ES_BLKS) * 256 + tid;  // 40960 exactly
        int j = idx & 7, lane = (idx >> 3) & 63, sub = (idx >> 9) & 15, g = idx >> 13;
        int kt = sub >> 2, ct = sub & 3;
        int k = kt * 32 + (lane >> 4) * 8 + j;
        int col = ct * 16 + (lane & 15);
        float v = (g < 4) ? W2[(g * D + k) * DO + col] : Wself2[k * DO + col];
        BF[idx] = f2bf(v);
    }
}

// ---- 4. k_fix: [0,256) in-register uncached rows -> histbf tail;
//        [256,384) params (one column per block) ----
__global__ void __launch_bounds__(256) k_fix(
        const float* __restrict__ x, const int* __restrict__ src1,
        const int* __restrict__ dst1, const int* __restrict__ et1,
        const float* __restrict__ W1, const float* __restrict__ Wself1,
        const float* __restrict__ b1, const int* __restrict__ cnt,
        const int* __restrict__ nuc, const int* __restrict__ list,
        const int* __restrict__ uc_node, const float* __restrict__ psum,
        const float* __restrict__ gamma, const float* __restrict__ beta,
        float* __restrict__ params, unsigned short* __restrict__ histbf) {
    int b = blockIdx.x, tid = threadIdx.x;
    if (b < 256) {
        int n = *nuc; if (n > UC_CAP) n = UC_CAP;
        if (b >= n) return;
        int node = uc_node[b];
        int c = tid & 127, half = tid >> 7, k0 = half * 64;
        float acc = (half == 0) ? b1[c] : 0.f;
        for (int k = k0; k < k0 + 64; k++)
            acc += x[(size_t)node * D + k] * Wself1[k * D + c];
        int nl = *cnt; if (nl > WL_CAP) nl = WL_CAP;
        for (int i2 = 0; i2 < nl; i2++) {
            int e = list[i2];
            if (dst1[e] != node) continue;
            int s = src1[e], t = et1[e];
            for (int k = k0; k < k0 + 64; k++)
                acc += x[(size_t)s * D + k] * W1[(t * D + k) * D + c];
        }
        __shared__ float red[256];
        red[tid] = acc;
        __syncthreads();
        if (half == 0)
            histbf[(size_t)(HBUF + b) * D + c] = f2bf(red[c] + red[128 + c]);
    } else {
        int c = b - 256;                        // [0,128)
        float S = 0.f, SS = 0.f;
        for (int r = tid; r < CONV_BLKS; r += 256) {
            S += psum[r * 256 + c];
            SS += psum[r * 256 + 128 + c];
        }
        __shared__ float r1[256], r2[256];
        r1[tid] = S; r2[tid] = SS;
        __syncthreads();
        for (int off = 128; off; off >>= 1) {
            if (tid < off) { r1[tid] += r1[tid + off]; r2[tid] += r2[tid + off]; }
            __syncthreads();
        }
        if (tid == 0) {
            float mean = r1[0] / (float)N1;
            float var = r2[0] / (float)N1 - mean * mean;
            float sc = gamma[c] * rsqrtf(var + 1e-5f);
            params[c] = sc;
            params[128 + c] = beta[c] - mean * sc;
        }
    }
}

// ---- 5. aggregate: block-per-dst, 4 waves; payload pre-remap'd ----
#define AGG_ACC(P, V) { \
    int t_ = (P) >> 16; \
    float f0_ = fmaxf(bf2f((V) & 0xffff) * sc0 + sh0, 0.f); \
    float f1_ = fmaxf(bf2f((V) >> 16) * sc1 + sh1, 0.f); \
    acc[0][0] += (t_ == 0) ? f0_ : 0.f; acc[0][1] += (t_ == 0) ? f1_ : 0.f; \
    acc[1][0] += (t_ == 1) ? f0_ : 0.f; acc[1][1] += (t_ == 1) ? f1_ : 0.f; \
    acc[2][0] += (t_ == 2) ? f0_ : 0.f; acc[2][1] += (t_ == 2) ? f1_ : 0.f; \
    acc[3][0] += (t_ == 3) ? f0_ : 0.f; acc[3][1] += (t_ == 3) ? f1_ : 0.f; }

__global__ void __launch_bounds__(256) k_agg(const unsigned int* __restrict__ hbu,
                                             const int* __restrict__ degcnt,
                                             const int* __restrict__ epay,
                                             const float* __restrict__ params,
                                             unsigned int* __restrict__ aggbu) {
    __shared__ float red[4 * 4 * 128];
    int d = blockIdx.x;
    int wave = threadIdx.x >> 6, lane = threadIdx.x & 63;
    float sc0 = params[2 * lane],     sh0 = params[128 + 2 * lane];
    float sc1 = params[2 * lane + 1], sh1 = params[128 + 2 * lane + 1];
    float acc[4][2] = {};
    int j1 = degcnt[d * 16]; if (j1 > CAP) j1 = CAP;
    const int* ep = epay + d * CAP;
    int j = wave;
    for (; j + 12 < j1; j += 16) {
        int p0 = ep[j], p1 = ep[j + 4], p2 = ep[j + 8], p3 = ep[j + 12];
        unsigned int v0 = hbu[(size_t)(p0 & 0xffff) * 64 + lane];
        unsigned int v1 = hbu[(size_t)(p1 & 0xffff) * 64 + lane];
        unsigned int v2 = hbu[(size_t)(p2 & 0xffff) * 64 + lane];
        unsigned int v3 = hbu[(size_t)(p3 & 0xffff) * 64 + lane];
        AGG_ACC(p0, v0); AGG_ACC(p1, v1); AGG_ACC(p2, v2); AGG_ACC(p3, v3);
    }
    for (; j < j1; j += 4) {
        int p = ep[j];
        unsigned int v = hbu[(size_t)(p & 0xffff) * 64 + lane];
        AGG_ACC(p, v);
    }
#pragma unroll
    for (int t = 0; t < 4; t++) {
        red[(wave * 4 + t) * 128 + 2 * lane]     = acc[t][0];
        red[(wave * 4 + t) * 128 + 2 * lane + 1] = acc[t][1];
    }
    __syncthreads();
    int t = threadIdx.x >> 6, l2 = threadIdx.x & 63;
    float s0 = 0.f, s1 = 0.f;
#pragma unroll
    for (int w = 0; w < 4; w++) {
        s0 += red[(w * 4 + t) * 128 + 2 * l2];
        s1 += red[(w * 4 + t) * 128 + 2 * l2 + 1];
    }
    aggbu[((size_t)t * N2 + d) * 64 + l2] =
        (unsigned int)f2bf(s0) | ((unsigned int)f2bf(s1) << 16);
}

// ---- 6. out[d] = logsoftmax(b2 + relu(bn(h[d]))@Wself2 + sum_t agg[t][d]@W2[t]) ----
__global__ void __launch_bounds__(256) k_gemm2(const unsigned short* __restrict__ aggb,
                                               const unsigned short* __restrict__ histbf,
                                               const int* __restrict__ remap,
                                               const unsigned short* __restrict__ BF,
                                               const float* __restrict__ params,
                                               const float* __restrict__ b2,
                                               float* __restrict__ out) {
    int row0 = blockIdx.x * 64;
    int wave = threadIdx.x >> 6, lane = threadIdx.x & 63;
    int r = row0 + wave * 16 + (lane & 15);
    int rl = (r < N2) ? r : N2 - 1;
    int ridx = remap[rl];
    int kb = (lane >> 4) * 8;
    f32x4 acc[4] = {};
#pragma unroll
    for (int kt = 0; kt < 4; kt++) {
#pragma unroll
        for (int g = 0; g < 5; g++) {
            bfrag8 a;
            if (g < 4) {
                a = *reinterpret_cast<const bfrag8*>(aggb + ((size_t)(g * N2 + rl) * D + kt * 32 + kb));
            } else {
                bfrag8 raw = *reinterpret_cast<const bfrag8*>(histbf + ((size_t)ridx * D + kt * 32 + kb));
#pragma unroll
                for (int j = 0; j < 8; j++) {
                    int c = kt * 32 + kb + j;
                    float f = bf2f((unsigned int)(unsigned short)raw[j]);
                    f = fmaxf(f * params[c] + params[128 + c], 0.f);
                    a[j] = (short)f2bf(f);
                }
            }
#pragma unroll
            for (int ct = 0; ct < 4; ct++) {
                bfrag8 bb = *reinterpret_cast<const bfrag8*>(BF + ((((g * 4 + kt) * 4 + ct) * 64 + lane) * 8));
                acc[ct] = __builtin_amdgcn_mfma_f32_16x16x32_bf16(a, bb, acc[ct], 0, 0, 0);
            }
        }
    }
    float bb4[4];
#pragma unroll
    for (int ct = 0; ct < 4; ct++) bb4[ct] = b2[ct * 16 + (lane & 15)];
    int srow = row0 + wave * 16 + (lane >> 4) * 4;
#pragma unroll
    for (int i = 0; i < 4; i++) {
        float v[4];
#pragma unroll
        for (int ct = 0; ct < 4; ct++) v[ct] = acc[ct][i] + bb4[ct];
        float m = fmaxf(fmaxf(v[0], v[1]), fmaxf(v[2], v[3]));
#pragma unroll
        for (int sh = 1; sh <= 8; sh <<= 1) m = fmaxf(m, __shfl_xor(m, sh, 64));
        float s = 0.f;
#pragma unroll
        for (int ct = 0; ct < 4; ct++) s += expf(v[ct] - m);
#pragma unroll
        for (int sh = 1; sh <= 8; sh <<= 1) s += __shfl_xor(s, sh, 64);
        float lg = m + logf(s);
        int rr = srow + i;
        if (rr < N2) {
#pragma unroll
            for (int ct = 0; ct < 4; ct++)
                out[(size_t)rr * DO + ct * 16 + (lane & 15)] = v[ct] - lg;
        }
    }
}

extern "C" void kernel_launch(void* const* d_in, const int* in_sizes, int n_in,
                              void* d_out, int out_size, void* d_ws, size_t ws_size,
                              hipStream_t stream) {
    const float* x      = (const float*)d_in[0];
    const int* src1     = (const int*)d_in[1];
    const int* dst1     = (const int*)d_in[2];
    const int* et1      = (const int*)d_in[3];
    const int* src2     = (const int*)d_in[4];
    const int* dst2     = (const int*)d_in[5];
    const int* et2      = (const int*)d_in[6];
    const int* hmap     = (const int*)d_in[7];
    const float* hist   = (const float*)d_in[8];
    const float* W1     = (const float*)d_in[9];
    const float* Wself1 = (const float*)d_in[10];
    const float* b1     = (const float*)d_in[11];
    const float* gamma  = (const float*)d_in[12];
    const float* beta   = (const float*)d_in[13];
    const float* W2     = (const float*)d_in[14];
    const float* Wself2 = (const float*)d_in[15];
    const float* b2     = (const float*)d_in[16];
    float* out = (float*)d_out;

    char* ws = (char*)d_ws;
    unsigned short* histbf = (unsigned short*)(ws);            //  7,745,536 (30256 rows)
    unsigned short* aggb   = (unsigned short*)(ws + 7745536);  //  6,144,000
    unsigned short* BF     = (unsigned short*)(ws + 13889536); //     81,920
    int* remap             = (int*)(ws + 13971456);            //    240,000
    int* epay              = (int*)(ws + 14211456);            //  4,608,000
    int* degcnt            = (int*)(ws + 18819456);            //    384,000 (padded x16)
    int* mcount            = (int*)(ws + 19203456);            //    120,000
    float* psum            = (float*)(ws + 19323456);          //    480,256
    int* list              = (int*)(ws + 19803712);            //    131,072
    int* uc_node           = (int*)(ws + 19934784);            //      1,024
    float* params          = (float*)(ws + 19935808);          //      1,024
    int* cnt               = (int*)(ws + 19936832);            //          4
    int* nuc               = (int*)(ws + 19936836);            //          4

    k_zero<<<128, 256, 0, stream>>>(mcount, degcnt, cnt, nuc);
    k_scan<<<(N1 + 255) / 256, 256, 0, stream>>>(hmap, mcount, nuc, uc_node, remap);
    k_big<<<CONV_BLKS + ES_BLKS + BFRAG_BLKS, 256, 0, stream>>>(
        hist, histbf, mcount, psum, hmap, remap,
        dst1, cnt, list, src2, dst2, et2, degcnt, epay, W2, Wself2, BF);
    k_fix<<<384, 256, 0, stream>>>(x, src1, dst1, et1, W1, Wself1, b1,
                                   cnt, nuc, list, uc_node, psum,
                                   gamma, beta, params, histbf);
    k_agg<<<N2, 256, 0, stream>>>((const unsigned int*)histbf, degcnt, epay,
                                  params, (unsigned int*)aggb);
    k_gemm2<<<94, 256, 0, stream>>>(aggb, histbf, remap, BF, params, b2, out);
}

// Round 16
// 98.927 us; speedup vs baseline: 1.2956x; 1.2956x over previous
//
#include <hip/hip_runtime.h>
#include <hip/hip_bf16.h>

#define N0 300000
#define N1 60000
#define N2 6000
#define E1 1200000
#define E2 300000
#define D 128
#define DO 64
#define HBUF 30000

#define WL_CAP 32768
#define UC_CAP 256
#define CAP 192               // per-dst edge bucket capacity (Poisson(50); max ~100)

#define CONV_BLKS 469         // x256 thr x4 it x8 elems = 480,256 chunks >= 480,000
#define ESCAN_BLKS 4688       // x256 >= E1
#define BFRAG_BLKS 160        // 40960 exactly

typedef __attribute__((ext_vector_type(8))) short bfrag8;
typedef __attribute__((ext_vector_type(4))) float f32x4;

__device__ __forceinline__ float bf2f(unsigned int u) {
    union { unsigned int i; float f; } c; c.i = u << 16; return c.f;
}
__device__ __forceinline__ unsigned short f2bf(float f) {
    return __bfloat16_as_ushort(__float2bfloat16(f));
}

// ---- 1. zero the accumulators (graph-replay safe) ----
__global__ void k_zero(float* __restrict__ hfix, int* __restrict__ mcount,
                       int* __restrict__ degcnt, int* __restrict__ cnt,
                       int* __restrict__ nuc) {
    int i = blockIdx.x * 256 + threadIdx.x;
    int stride = gridDim.x * 256;
    for (int j = i; j < UC_CAP * D; j += stride) hfix[j] = 0.f;
    for (int j = i; j < HBUF; j += stride) mcount[j] = 0;
    for (int j = i; j < N2 * 16; j += stride) degcnt[j] = 0;
    if (i == 0) { *cnt = 0; *nuc = 0; }
}

// ---- 2. node scan: mcount histogram + uncached registration + remap build ----
__global__ void k_scan(const int* __restrict__ hmap, int* __restrict__ mcount,
                       int* __restrict__ nuc, int* __restrict__ uc_node,
                       int* __restrict__ remap) {
    int node = blockIdx.x * 256 + threadIdx.x;
    if (node >= N1) return;
    int m = hmap[node];
    if (m >= 0) {
        atomicAdd(&mcount[m], 1);
        remap[node] = m;
    } else {
        int slot = atomicAdd(nuc, 1);
        if (slot > UC_CAP - 1) slot = UC_CAP - 1;
        uc_node[slot] = node;
        remap[node] = HBUF + slot;
    }
}

// ---- 3. k_A: [0,469) hist->bf16 convert + fused weighted BN-stats partials;
//        [469,5157) E1 worklist scan + E2 bucket scatter (remap'd payload);
//        [5157,5317) bfrag ----
__global__ void __launch_bounds__(256) k_A(
        const float* __restrict__ hist, unsigned short* __restrict__ histbf,
        const int* __restrict__ mcount, float* __restrict__ psum,
        const int* __restrict__ hmap, const int* __restrict__ remap,
        const int* __restrict__ dst1, int* __restrict__ cnt, int* __restrict__ list,
        const int* __restrict__ src2, const int* __restrict__ dst2,
        const int* __restrict__ et2, int* __restrict__ degcnt,
        int* __restrict__ epay,
        const float* __restrict__ W2, const float* __restrict__ Wself2,
        unsigned short* __restrict__ BF) {
    int b = blockIdx.x, tid = threadIdx.x;
    if (b < CONV_BLKS) {
        __shared__ float ls1[2048], ls2[2048];
        float s[8] = {0,0,0,0,0,0,0,0}, ss[8] = {0,0,0,0,0,0,0,0};
        const float4* h4 = (const float4*)hist;
#pragma unroll
        for (int it = 0; it < 4; it++) {
            int i = (b * 4 + it) * 256 + tid;      // thread-chunk of 8 elems
            if (i >= 480000) break;                // 3.84M/8
            int row = i >> 4;                      // 16 chunks per row
            float w = (float)mcount[row];
            float4 u = h4[(size_t)i * 2], v = h4[(size_t)i * 2 + 1];
            float e[8] = {u.x, u.y, u.z, u.w, v.x, v.y, v.z, v.w};
            union { unsigned short q[8]; uint4 o; } o;
#pragma unroll
            for (int j = 0; j < 8; j++) {
                o.q[j] = f2bf(e[j]);
                s[j] += w * e[j];
                ss[j] += w * e[j] * e[j];
            }
            *(uint4*)(histbf + (size_t)i * 8) = o.o;
        }
#pragma unroll
        for (int j = 0; j < 8; j++) { ls1[tid * 8 + j] = s[j]; ls2[tid * 8 + j] = ss[j]; }
        __syncthreads();
        if (tid < 128) {
            int qq = tid >> 3, jj = tid & 7;       // col c = tid = (t&15)*8+j
            float S = 0.f, SS = 0.f;
#pragma unroll
            for (int g = 0; g < 16; g++) {
                int src = (qq + 16 * g) * 8 + jj;
                S += ls1[src]; SS += ls2[src];
            }
            psum[b * 256 + tid] = S;
            psum[b * 256 + 128 + tid] = SS;
        }
    } else if (b < CONV_BLKS + ESCAN_BLKS) {
        int e = (b - CONV_BLKS) * 256 + tid;
        if (e < E2) {
            int d = dst2[e];
            int pos = atomicAdd(&degcnt[d * 16], 1);
            if (pos < CAP) epay[d * CAP + pos] = remap[src2[e]] | (et2[e] << 16);
        }
        if (e < E1 && hmap[dst1[e]] < 0) {
            int i = atomicAdd(cnt, 1);
            if (i < WL_CAP) list[i] = e;
        }
    } else {
        int idx = (b - CONV_BLKS - ESCAN_BLKS) * 256 + tid;  // 40960 exactly
        int j = idx & 7, lane = (idx >> 3) & 63, sub = (idx >> 9) & 15, g = idx >> 13;
        int kt = sub >> 2, ct = sub & 3;
        int k = kt * 32 + (lane >> 4) * 8 + j;
        int col = ct * 16 + (lane & 15);
        float v = (g < 4) ? W2[(g * D + k) * DO + col] : Wself2[k * DO + col];
        BF[idx] = f2bf(v);
    }
}

// ---- 4. k_wl2: [0,16) worklist edges; [16,24) selfloop for uncached;
//        [24,40) psum 469-row reduce to psum2 16 rows ----
__global__ void __launch_bounds__(256) k_wl2(
        const float* __restrict__ x, const int* __restrict__ src1,
        const int* __restrict__ dst1, const int* __restrict__ et1,
        const float* __restrict__ W1, const float* __restrict__ Wself1,
        const float* __restrict__ b1, const int* __restrict__ cnt,
        const int* __restrict__ list, const int* __restrict__ remap,
        const int* __restrict__ uc_node, const int* __restrict__ nuc,
        float* __restrict__ hfix, const float* __restrict__ psum,
        float* __restrict__ psum2) {
    int b = blockIdx.x, tid = threadIdx.x;
    if (b < 16) {
        int c = tid & 127, half = tid >> 7;
        int n = *cnt; if (n > WL_CAP) n = WL_CAP;
        for (int i = b * 2 + half; i < n; i += 32) {
            int e = list[i];
            int s = src1[e], d = dst1[e], t = et1[e];
            int slot = remap[d] - HBUF;
            if (slot < 0 || slot >= UC_CAP) continue;
            float acc = 0.f;
            for (int k = 0; k < D; k++) acc += x[(size_t)s * D + k] * W1[(t * D + k) * D + c];
            atomicAdd(&hfix[slot * D + c], acc);
        }
    } else if (b < 24) {
        int n = *nuc; if (n > UC_CAP) n = UC_CAP;
        int c = tid & 127, half = tid >> 7;
        for (int slot = (b - 16) * 2 + half; slot < n; slot += 16) {
            int node = uc_node[slot];
            float acc = b1[c];
            for (int k = 0; k < D; k++) acc += x[(size_t)node * D + k] * Wself1[k * D + c];
            atomicAdd(&hfix[slot * D + c], acc);
        }
    } else {
        int r = b - 24;                        // [0,16)
        float S = 0.f;
        for (int i = r; i < CONV_BLKS; i += 16) S += psum[i * 256 + tid];
        psum2[r * 256 + tid] = S;
    }
}

// ---- 5. k_mid: b0 params (psum2 + exact hfix term); b1 histbf tail rows ----
__global__ void k_mid(const float* __restrict__ psum2, const float* __restrict__ hfix,
                      const int* __restrict__ nuc,
                      const float* __restrict__ gamma, const float* __restrict__ beta,
                      float* __restrict__ params,
                      unsigned short* __restrict__ histbf) {
    int b = blockIdx.x, tid = threadIdx.x;
    if (b == 0) {
        if (tid < 128) {
            float S = 0.f, SS = 0.f;
#pragma unroll
            for (int r = 0; r < 16; r++) {
                S += psum2[r * 256 + tid];
                SS += psum2[r * 256 + 128 + tid];
            }
            int n = *nuc; if (n > UC_CAP) n = UC_CAP;
            for (int slot = 0; slot < n; slot++) {
                float v = hfix[slot * D + tid];
                S += v; SS += v * v;
            }
            float mean = S / (float)N1;
            float var = SS / (float)N1 - mean * mean;
            float sc = gamma[tid] * rsqrtf(var + 1e-5f);
            params[tid] = sc;
            params[128 + tid] = beta[tid] - mean * sc;
        }
    } else {
        for (int i = tid; i < UC_CAP * D; i += 256)
            histbf[(size_t)HBUF * D + i] = f2bf(hfix[i]);
    }
}

// ---- 6. aggregate: block-per-dst, 4 waves; payload pre-remap'd ----
#define AGG_ACC(P, V) { \
    int t_ = (P) >> 16; \
    float f0_ = fmaxf(bf2f((V) & 0xffff) * sc0 + sh0, 0.f); \
    float f1_ = fmaxf(bf2f((V) >> 16) * sc1 + sh1, 0.f); \
    acc[0][0] += (t_ == 0) ? f0_ : 0.f; acc[0][1] += (t_ == 0) ? f1_ : 0.f; \
    acc[1][0] += (t_ == 1) ? f0_ : 0.f; acc[1][1] += (t_ == 1) ? f1_ : 0.f; \
    acc[2][0] += (t_ == 2) ? f0_ : 0.f; acc[2][1] += (t_ == 2) ? f1_ : 0.f; \
    acc[3][0] += (t_ == 3) ? f0_ : 0.f; acc[3][1] += (t_ == 3) ? f1_ : 0.f; }

__global__ void __launch_bounds__(256) k_agg(const unsigned int* __restrict__ hbu,
                                             const int* __restrict__ degcnt,
                                             const int* __restrict__ epay,
                                             const float* __restrict__ params,
                                             unsigned int* __restrict__ aggbu) {
    __shared__ float red[4 * 4 * 128];
    int d = blockIdx.x;
    int wave = threadIdx.x >> 6, lane = threadIdx.x & 63;
    float sc0 = params[2 * lane],     sh0 = params[128 + 2 * lane];
    float sc1 = params[2 * lane + 1], sh1 = params[128 + 2 * lane + 1];
    float acc[4][2] = {};
    int j1 = degcnt[d * 16]; if (j1 > CAP) j1 = CAP;
    const int* ep = epay + d * CAP;
    int j = wave;
    for (; j + 12 < j1; j += 16) {
        int p0 = ep[j], p1 = ep[j + 4], p2 = ep[j + 8], p3 = ep[j + 12];
        unsigned int v0 = hbu[(size_t)(p0 & 0xffff) * 64 + lane];
        unsigned int v1 = hbu[(size_t)(p1 & 0xffff) * 64 + lane];
        unsigned int v2 = hbu[(size_t)(p2 & 0xffff) * 64 + lane];
        unsigned int v3 = hbu[(size_t)(p3 & 0xffff) * 64 + lane];
        AGG_ACC(p0, v0); AGG_ACC(p1, v1); AGG_ACC(p2, v2); AGG_ACC(p3, v3);
    }
    for (; j < j1; j += 4) {
        int p = ep[j];
        unsigned int v = hbu[(size_t)(p & 0xffff) * 64 + lane];
        AGG_ACC(p, v);
    }
#pragma unroll
    for (int t = 0; t < 4; t++) {
        red[(wave * 4 + t) * 128 + 2 * lane]     = acc[t][0];
        red[(wave * 4 + t) * 128 + 2 * lane + 1] = acc[t][1];
    }
    __syncthreads();
    int t = threadIdx.x >> 6, l2 = threadIdx.x & 63;
    float s0 = 0.f, s1 = 0.f;
#pragma unroll
    for (int w = 0; w < 4; w++) {
        s0 += red[(w * 4 + t) * 128 + 2 * l2];
        s1 += red[(w * 4 + t) * 128 + 2 * l2 + 1];
    }
    aggbu[((size_t)t * N2 + d) * 64 + l2] =
        (unsigned int)f2bf(s0) | ((unsigned int)f2bf(s1) << 16);
}

// ---- 7. out[d] = logsoftmax(b2 + relu(bn(h[d]))@Wself2 + sum_t agg[t][d]@W2[t]) ----
__global__ void __launch_bounds__(256) k_gemm2(const unsigned short* __restrict__ aggb,
                                               const unsigned short* __restrict__ histbf,
                                               const int* __restrict__ remap,
                                               const unsigned short* __restrict__ BF,
                                               const float* __restrict__ params,
                                               const float* __restrict__ b2,
                                               float* __restrict__ out) {
    int row0 = blockIdx.x * 64;
    int wave = threadIdx.x >> 6, lane = threadIdx.x & 63;
    int r = row0 + wave * 16 + (lane & 15);
    int rl = (r < N2) ? r : N2 - 1;
    int ridx = remap[rl];
    int kb = (lane >> 4) * 8;
    f32x4 acc[4] = {};
#pragma unroll
    for (int kt = 0; kt < 4; kt++) {
#pragma unroll
        for (int g = 0; g < 5; g++) {
            bfrag8 a;
            if (g < 4) {
                a = *reinterpret_cast<const bfrag8*>(aggb + ((size_t)(g * N2 + rl) * D + kt * 32 + kb));
            } else {
                bfrag8 raw = *reinterpret_cast<const bfrag8*>(histbf + ((size_t)ridx * D + kt * 32 + kb));
#pragma unroll
                for (int j = 0; j < 8; j++) {
                    int c = kt * 32 + kb + j;
                    float f = bf2f((unsigned int)(unsigned short)raw[j]);
                    f = fmaxf(f * params[c] + params[128 + c], 0.f);
                    a[j] = (short)f2bf(f);
                }
            }
#pragma unroll
            for (int ct = 0; ct < 4; ct++) {
                bfrag8 bb = *reinterpret_cast<const bfrag8*>(BF + ((((g * 4 + kt) * 4 + ct) * 64 + lane) * 8));
                acc[ct] = __builtin_amdgcn_mfma_f32_16x16x32_bf16(a, bb, acc[ct], 0, 0, 0);
            }
        }
    }
    float bb4[4];
#pragma unroll
    for (int ct = 0; ct < 4; ct++) bb4[ct] = b2[ct * 16 + (lane & 15)];
    int srow = row0 + wave * 16 + (lane >> 4) * 4;
#pragma unroll
    for (int i = 0; i < 4; i++) {
        float v[4];
#pragma unroll
        for (int ct = 0; ct < 4; ct++) v[ct] = acc[ct][i] + bb4[ct];
        float m = fmaxf(fmaxf(v[0], v[1]), fmaxf(v[2], v[3]));
#pragma unroll
        for (int sh = 1; sh <= 8; sh <<= 1) m = fmaxf(m, __shfl_xor(m, sh, 64));
        float s = 0.f;
#pragma unroll
        for (int ct = 0; ct < 4; ct++) s += expf(v[ct] - m);
#pragma unroll
        for (int sh = 1; sh <= 8; sh <<= 1) s += __shfl_xor(s, sh, 64);
        float lg = m + logf(s);
        int rr = srow + i;
        if (rr < N2) {
#pragma unroll
            for (int ct = 0; ct < 4; ct++)
                out[(size_t)rr * DO + ct * 16 + (lane & 15)] = v[ct] - lg;
        }
    }
}

extern "C" void kernel_launch(void* const* d_in, const int* in_sizes, int n_in,
                              void* d_out, int out_size, void* d_ws, size_t ws_size,
                              hipStream_t stream) {
    const float* x      = (const float*)d_in[0];
    const int* src1     = (const int*)d_in[1];
    const int* dst1     = (const int*)d_in[2];
    const int* et1      = (const int*)d_in[3];
    const int* src2     = (const int*)d_in[4];
    const int* dst2     = (const int*)d_in[5];
    const int* et2      = (const int*)d_in[6];
    const int* hmap     = (const int*)d_in[7];
    const float* hist   = (const float*)d_in[8];
    const float* W1     = (const float*)d_in[9];
    const float* Wself1 = (const float*)d_in[10];
    const float* b1     = (const float*)d_in[11];
    const float* gamma  = (const float*)d_in[12];
    const float* beta   = (const float*)d_in[13];
    const float* W2     = (const float*)d_in[14];
    const float* Wself2 = (const float*)d_in[15];
    const float* b2     = (const float*)d_in[16];
    float* out = (float*)d_out;

    char* ws = (char*)d_ws;
    unsigned short* histbf = (unsigned short*)(ws);            //  7,745,536 (30256 rows)
    unsigned short* aggb   = (unsigned short*)(ws + 7745536);  //  6,144,000
    unsigned short* BF     = (unsigned short*)(ws + 13889536); //     81,920
    float* hfix            = (float*)(ws + 13971456);          //    131,072
    int* uc_node           = (int*)(ws + 14102528);            //      1,024
    int* remap             = (int*)(ws + 14103552);            //    240,000
    int* epay              = (int*)(ws + 14343552);            //  4,608,000
    int* mcount            = (int*)(ws + 18951552);            //    120,000
    int* degcnt            = (int*)(ws + 19071552);            //    384,000 (padded x16)
    float* psum            = (float*)(ws + 19455552);          //    480,256
    float* psum2           = (float*)(ws + 19935808);          //     16,384
    int* list              = (int*)(ws + 19952192);            //    131,072
    float* params          = (float*)(ws + 20083264);          //      1,024
    int* cnt               = (int*)(ws + 20084288);            //          4
    int* nuc               = (int*)(ws + 20084292);            //          4

    k_zero<<<128, 256, 0, stream>>>(hfix, mcount, degcnt, cnt, nuc);
    k_scan<<<(N1 + 255) / 256, 256, 0, stream>>>(hmap, mcount, nuc, uc_node, remap);
    k_A<<<CONV_BLKS + ESCAN_BLKS + BFRAG_BLKS, 256, 0, stream>>>(
        hist, histbf, mcount, psum, hmap, remap,
        dst1, cnt, list, src2, dst2, et2, degcnt, epay, W2, Wself2, BF);
    k_wl2<<<40, 256, 0, stream>>>(x, src1, dst1, et1, W1, Wself1, b1,
                                  cnt, list, remap, uc_node, nuc,
                                  hfix, psum, psum2);
    k_mid<<<2, 256, 0, stream>>>(psum2, hfix, nuc, gamma, beta, params, histbf);
    k_agg<<<N2, 256, 0, stream>>>((const unsigned int*)histbf, degcnt, epay,
                                  params, (unsigned int*)aggb);
    k_gemm2<<<94, 256, 0, stream>>>(aggb, histbf, remap, BF, params, b2, out);
}

// Round 18
// 93.393 us; speedup vs baseline: 1.3723x; 1.0593x over previous
//
#include <hip/hip_runtime.h>
#include <hip/hip_bf16.h>

#define N0 300000
#define N1 60000
#define N2 6000
#define E1 1200000
#define E2 300000
#define D 128
#define DO 64
#define HBUF 30000

#define WL_CAP 32768
#define UC_CAP 256
#define CAP 192               // per-dst edge bucket capacity (Poisson(50); max ~100)

#define CONV_BLKS 469         // x256 thr x4 it x8 elems = 480,256 chunks >= 480,000
#define ESCAN_BLKS 4688       // x256 >= E1
#define BFRAG_BLKS 160        // 40960 exactly

typedef __attribute__((ext_vector_type(8))) short bfrag8;
typedef __attribute__((ext_vector_type(4))) float f32x4;

__device__ __forceinline__ float bf2f(unsigned int u) {
    union { unsigned int i; float f; } c; c.i = u << 16; return c.f;
}
__device__ __forceinline__ unsigned short f2bf(float f) {
    return __bfloat16_as_ushort(__float2bfloat16(f));
}

// ---- 1. zero the accumulators (graph-replay safe) ----
__global__ void k_zero(float* __restrict__ hfix, int* __restrict__ mcount,
                       int* __restrict__ degcnt, int* __restrict__ cnt,
                       int* __restrict__ nuc) {
    int i = blockIdx.x * 256 + threadIdx.x;
    int stride = gridDim.x * 256;
    for (int j = i; j < UC_CAP * D; j += stride) hfix[j] = 0.f;
    for (int j = i; j < HBUF; j += stride) mcount[j] = 0;
    for (int j = i; j < N2 * 16; j += stride) degcnt[j] = 0;
    if (i == 0) { *cnt = 0; *nuc = 0; }
}

// ---- 2. node scan: mcount histogram + uncached registration + remap build ----
__global__ void k_scan(const int* __restrict__ hmap, int* __restrict__ mcount,
                       int* __restrict__ nuc, int* __restrict__ uc_node,
                       int* __restrict__ remap) {
    int node = blockIdx.x * 256 + threadIdx.x;
    if (node >= N1) return;
    int m = hmap[node];
    if (m >= 0) {
        atomicAdd(&mcount[m], 1);
        remap[node] = m;
    } else {
        int slot = atomicAdd(nuc, 1);
        if (slot > UC_CAP - 1) slot = UC_CAP - 1;
        uc_node[slot] = node;
        remap[node] = HBUF + slot;
    }
}

// ---- 3. k_A: [0,469) hist->bf16 convert + fused weighted BN-stats partials;
//        [469,5157) E1 worklist scan + E2 bucket scatter (remap'd payload);
//        [5157,5317) bfrag ----
__global__ void __launch_bounds__(256) k_A(
        const float* __restrict__ hist, unsigned short* __restrict__ histbf,
        const int* __restrict__ mcount, float* __restrict__ psum,
        const int* __restrict__ hmap, const int* __restrict__ remap,
        const int* __restrict__ dst1, int* __restrict__ cnt, int* __restrict__ list,
        const int* __restrict__ src2, const int* __restrict__ dst2,
        const int* __restrict__ et2, int* __restrict__ degcnt,
        int* __restrict__ epay,
        const float* __restrict__ W2, const float* __restrict__ Wself2,
        unsigned short* __restrict__ BF) {
    int b = blockIdx.x, tid = threadIdx.x;
    if (b < CONV_BLKS) {
        __shared__ float ls1[2048], ls2[2048];
        float s[8] = {0,0,0,0,0,0,0,0}, ss[8] = {0,0,0,0,0,0,0,0};
        const float4* h4 = (const float4*)hist;
#pragma unroll
        for (int it = 0; it < 4; it++) {
            int i = (b * 4 + it) * 256 + tid;      // thread-chunk of 8 elems
            if (i >= 480000) break;                // 3.84M/8
            int row = i >> 4;                      // 16 chunks per row
            float w = (float)mcount[row];
            float4 u = h4[(size_t)i * 2], v = h4[(size_t)i * 2 + 1];
            float e[8] = {u.x, u.y, u.z, u.w, v.x, v.y, v.z, v.w};
            union { unsigned short q[8]; uint4 o; } o;
#pragma unroll
            for (int j = 0; j < 8; j++) {
                o.q[j] = f2bf(e[j]);
                s[j] += w * e[j];
                ss[j] += w * e[j] * e[j];
            }
            *(uint4*)(histbf + (size_t)i * 8) = o.o;
        }
#pragma unroll
        for (int j = 0; j < 8; j++) { ls1[tid * 8 + j] = s[j]; ls2[tid * 8 + j] = ss[j]; }
        __syncthreads();
        if (tid < 128) {
            int qq = tid >> 3, jj = tid & 7;       // col c = tid = (t&15)*8+j
            float S = 0.f, SS = 0.f;
#pragma unroll
            for (int g = 0; g < 16; g++) {
                int src = (qq + 16 * g) * 8 + jj;
                S += ls1[src]; SS += ls2[src];
            }
            psum[b * 256 + tid] = S;
            psum[b * 256 + 128 + tid] = SS;
        }
    } else if (b < CONV_BLKS + ESCAN_BLKS) {
        int e = (b - CONV_BLKS) * 256 + tid;
        if (e < E2) {
            int d = dst2[e];
            int pos = atomicAdd(&degcnt[d * 16], 1);
            if (pos < CAP) epay[d * CAP + pos] = remap[src2[e]] | (et2[e] << 16);
        }
        if (e < E1 && hmap[dst1[e]] < 0) {
            int i = atomicAdd(cnt, 1);
            if (i < WL_CAP) list[i] = e;
        }
    } else {
        int idx = (b - CONV_BLKS - ESCAN_BLKS) * 256 + tid;  // 40960 exactly
        int j = idx & 7, lane = (idx >> 3) & 63, sub = (idx >> 9) & 15, g = idx >> 13;
        int kt = sub >> 2, ct = sub & 3;
        int k = kt * 32 + (lane >> 4) * 8 + j;
        int col = ct * 16 + (lane & 15);
        float v = (g < 4) ? W2[(g * D + k) * DO + col] : Wself2[k * DO + col];
        BF[idx] = f2bf(v);
    }
}

// ---- 4. k_wl2: [0,64) worklist edges (1 edge per (block,half) slot);
//        [64,72) selfloop for uncached; [72,88) psum reduce to psum2 ----
__global__ void __launch_bounds__(256) k_wl2(
        const float* __restrict__ x, const int* __restrict__ src1,
        const int* __restrict__ dst1, const int* __restrict__ et1,
        const float* __restrict__ W1, const float* __restrict__ Wself1,
        const float* __restrict__ b1, const int* __restrict__ cnt,
        const int* __restrict__ list, const int* __restrict__ remap,
        const int* __restrict__ uc_node, const int* __restrict__ nuc,
        float* __restrict__ hfix, const float* __restrict__ psum,
        float* __restrict__ psum2) {
    int b = blockIdx.x, tid = threadIdx.x;
    if (b < 64) {
        int c = tid & 127, half = tid >> 7;
        int n = *cnt; if (n > WL_CAP) n = WL_CAP;
        for (int i = b * 2 + half; i < n; i += 128) {
            int e = list[i];
            int s = src1[e], d = dst1[e], t = et1[e];
            int slot = remap[d] - HBUF;
            if (slot < 0 || slot >= UC_CAP) continue;
            float acc = 0.f;
#pragma unroll 4
            for (int k = 0; k < D; k++) acc += x[(size_t)s * D + k] * W1[(t * D + k) * D + c];
            atomicAdd(&hfix[slot * D + c], acc);
        }
    } else if (b < 72) {
        int n = *nuc; if (n > UC_CAP) n = UC_CAP;
        int c = tid & 127, half = tid >> 7;
        for (int slot = (b - 64) * 2 + half; slot < n; slot += 16) {
            int node = uc_node[slot];
            float acc = b1[c];
#pragma unroll 4
            for (int k = 0; k < D; k++) acc += x[(size_t)node * D + k] * Wself1[k * D + c];
            atomicAdd(&hfix[slot * D + c], acc);
        }
    } else {
        int r = b - 72;                        // [0,16)
        float S = 0.f;
        for (int i = r; i < CONV_BLKS; i += 16) S += psum[i * 256 + tid];
        psum2[r * 256 + tid] = S;
    }
}

// ---- 5. k_mid: b0 params (psum2 + exact hfix term); b1 histbf tail rows ----
__global__ void k_mid(const float* __restrict__ psum2, const float* __restrict__ hfix,
                      const int* __restrict__ nuc,
                      const float* __restrict__ gamma, const float* __restrict__ beta,
                      float* __restrict__ params,
                      unsigned short* __restrict__ histbf) {
    int b = blockIdx.x, tid = threadIdx.x;
    if (b == 0) {
        if (tid < 128) {
            float S = 0.f, SS = 0.f;
#pragma unroll
            for (int r = 0; r < 16; r++) {
                S += psum2[r * 256 + tid];
                SS += psum2[r * 256 + 128 + tid];
            }
            int n = *nuc; if (n > UC_CAP) n = UC_CAP;
            for (int slot = 0; slot < n; slot++) {
                float v = hfix[slot * D + tid];
                S += v; SS += v * v;
            }
            float mean = S / (float)N1;
            float var = SS / (float)N1 - mean * mean;
            float sc = gamma[tid] * rsqrtf(var + 1e-5f);
            params[tid] = sc;
            params[128 + tid] = beta[tid] - mean * sc;
        }
    } else {
        for (int i = tid; i < UC_CAP * D; i += 256)
            histbf[(size_t)HBUF * D + i] = f2bf(hfix[i]);
    }
}

// ---- 6. aggregate: block-per-dst, 4 waves, 8-deep in-flight gathers ----
#define AGG_ACC(P, V) { \
    int t_ = (P) >> 16; \
    float f0_ = fmaxf(bf2f((V) & 0xffff) * sc0 + sh0, 0.f); \
    float f1_ = fmaxf(bf2f((V) >> 16) * sc1 + sh1, 0.f); \
    acc[0][0] += (t_ == 0) ? f0_ : 0.f; acc[0][1] += (t_ == 0) ? f1_ : 0.f; \
    acc[1][0] += (t_ == 1) ? f0_ : 0.f; acc[1][1] += (t_ == 1) ? f1_ : 0.f; \
    acc[2][0] += (t_ == 2) ? f0_ : 0.f; acc[2][1] += (t_ == 2) ? f1_ : 0.f; \
    acc[3][0] += (t_ == 3) ? f0_ : 0.f; acc[3][1] += (t_ == 3) ? f1_ : 0.f; }

__global__ void __launch_bounds__(256) k_agg(const unsigned int* __restrict__ hbu,
                                             const int* __restrict__ degcnt,
                                             const int* __restrict__ epay,
                                             const float* __restrict__ params,
                                             unsigned int* __restrict__ aggbu) {
    __shared__ float red[4 * 4 * 128];
    int d = blockIdx.x;
    int wave = threadIdx.x >> 6, lane = threadIdx.x & 63;
    float sc0 = params[2 * lane],     sh0 = params[128 + 2 * lane];
    float sc1 = params[2 * lane + 1], sh1 = params[128 + 2 * lane + 1];
    float acc[4][2] = {};
    int j1 = degcnt[d * 16]; if (j1 > CAP) j1 = CAP;
    const int* ep = epay + d * CAP;
    int j = wave;
    // 8 gathers in flight per wave (stride 4 waves x 8 unroll = 32)
    for (; j + 28 < j1; j += 32) {
        int p0 = ep[j],      p1 = ep[j + 4],  p2 = ep[j + 8],  p3 = ep[j + 12];
        int p4 = ep[j + 16], p5 = ep[j + 20], p6 = ep[j + 24], p7 = ep[j + 28];
        unsigned int v0 = hbu[(size_t)(p0 & 0xffff) * 64 + lane];
        unsigned int v1 = hbu[(size_t)(p1 & 0xffff) * 64 + lane];
        unsigned int v2 = hbu[(size_t)(p2 & 0xffff) * 64 + lane];
        unsigned int v3 = hbu[(size_t)(p3 & 0xffff) * 64 + lane];
        unsigned int v4 = hbu[(size_t)(p4 & 0xffff) * 64 + lane];
        unsigned int v5 = hbu[(size_t)(p5 & 0xffff) * 64 + lane];
        unsigned int v6 = hbu[(size_t)(p6 & 0xffff) * 64 + lane];
        unsigned int v7 = hbu[(size_t)(p7 & 0xffff) * 64 + lane];
        AGG_ACC(p0, v0); AGG_ACC(p1, v1); AGG_ACC(p2, v2); AGG_ACC(p3, v3);
        AGG_ACC(p4, v4); AGG_ACC(p5, v5); AGG_ACC(p6, v6); AGG_ACC(p7, v7);
    }
    for (; j + 12 < j1; j += 16) {
        int p0 = ep[j], p1 = ep[j + 4], p2 = ep[j + 8], p3 = ep[j + 12];
        unsigned int v0 = hbu[(size_t)(p0 & 0xffff) * 64 + lane];
        unsigned int v1 = hbu[(size_t)(p1 & 0xffff) * 64 + lane];
        unsigned int v2 = hbu[(size_t)(p2 & 0xffff) * 64 + lane];
        unsigned int v3 = hbu[(size_t)(p3 & 0xffff) * 64 + lane];
        AGG_ACC(p0, v0); AGG_ACC(p1, v1); AGG_ACC(p2, v2); AGG_ACC(p3, v3);
    }
    for (; j < j1; j += 4) {
        int p = ep[j];
        unsigned int v = hbu[(size_t)(p & 0xffff) * 64 + lane];
        AGG_ACC(p, v);
    }
#pragma unroll
    for (int t = 0; t < 4; t++) {
        red[(wave * 4 + t) * 128 + 2 * lane]     = acc[t][0];
        red[(wave * 4 + t) * 128 + 2 * lane + 1] = acc[t][1];
    }
    __syncthreads();
    int t = threadIdx.x >> 6, l2 = threadIdx.x & 63;
    float s0 = 0.f, s1 = 0.f;
#pragma unroll
    for (int w = 0; w < 4; w++) {
        s0 += red[(w * 4 + t) * 128 + 2 * l2];
        s1 += red[(w * 4 + t) * 128 + 2 * l2 + 1];
    }
    aggbu[((size_t)t * N2 + d) * 64 + l2] =
        (unsigned int)f2bf(s0) | ((unsigned int)f2bf(s1) << 16);
}

// ---- 7. out[d] = logsoftmax(b2 + relu(bn(h[d]))@Wself2 + sum_t agg[t][d]@W2[t]) ----
__global__ void __launch_bounds__(256) k_gemm2(const unsigned short* __restrict__ aggb,
                                               const unsigned short* __restrict__ histbf,
                                               const int* __restrict__ remap,
                                               const unsigned short* __restrict__ BF,
                                               const float* __restrict__ params,
                                               const float* __restrict__ b2,
                                               float* __restrict__ out) {
    int row0 = blockIdx.x * 64;
    int wave = threadIdx.x >> 6, lane = threadIdx.x & 63;
    int r = row0 + wave * 16 + (lane & 15);
    int rl = (r < N2) ? r : N2 - 1;
    int ridx = remap[rl];
    int kb = (lane >> 4) * 8;
    f32x4 acc[4] = {};
#pragma unroll
    for (int kt = 0; kt < 4; kt++) {
#pragma unroll
        for (int g = 0; g < 5; g++) {
            bfrag8 a;
            if (g < 4) {
                a = *reinterpret_cast<const bfrag8*>(aggb + ((size_t)(g * N2 + rl) * D + kt * 32 + kb));
            } else {
                bfrag8 raw = *reinterpret_cast<const bfrag8*>(histbf + ((size_t)ridx * D + kt * 32 + kb));
#pragma unroll
                for (int j = 0; j < 8; j++) {
                    int c = kt * 32 + kb + j;
                    float f = bf2f((unsigned int)(unsigned short)raw[j]);
                    f = fmaxf(f * params[c] + params[128 + c], 0.f);
                    a[j] = (short)f2bf(f);
                }
            }
#pragma unroll
            for (int ct = 0; ct < 4; ct++) {
                bfrag8 bb = *reinterpret_cast<const bfrag8*>(BF + ((((g * 4 + kt) * 4 + ct) * 64 + lane) * 8));
                acc[ct] = __builtin_amdgcn_mfma_f32_16x16x32_bf16(a, bb, acc[ct], 0, 0, 0);
            }
        }
    }
    float bb4[4];
#pragma unroll
    for (int ct = 0; ct < 4; ct++) bb4[ct] = b2[ct * 16 + (lane & 15)];
    int srow = row0 + wave * 16 + (lane >> 4) * 4;
#pragma unroll
    for (int i = 0; i < 4; i++) {
        float v[4];
#pragma unroll
        for (int ct = 0; ct < 4; ct++) v[ct] = acc[ct][i] + bb4[ct];
        float m = fmaxf(fmaxf(v[0], v[1]), fmaxf(v[2], v[3]));
#pragma unroll
        for (int sh = 1; sh <= 8; sh <<= 1) m = fmaxf(m, __shfl_xor(m, sh, 64));
        float s = 0.f;
#pragma unroll
        for (int ct = 0; ct < 4; ct++) s += expf(v[ct] - m);
#pragma unroll
        for (int sh = 1; sh <= 8; sh <<= 1) s += __shfl_xor(s, sh, 64);
        float lg = m + logf(s);
        int rr = srow + i;
        if (rr < N2) {
#pragma unroll
            for (int ct = 0; ct < 4; ct++)
                out[(size_t)rr * DO + ct * 16 + (lane & 15)] = v[ct] - lg;
        }
    }
}

extern "C" void kernel_launch(void* const* d_in, const int* in_sizes, int n_in,
                              void* d_out, int out_size, void* d_ws, size_t ws_size,
                              hipStream_t stream) {
    const float* x      = (const float*)d_in[0];
    const int* src1     = (const int*)d_in[1];
    const int* dst1     = (const int*)d_in[2];
    const int* et1      = (const int*)d_in[3];
    const int* src2     = (const int*)d_in[4];
    const int* dst2     = (const int*)d_in[5];
    const int* et2      = (const int*)d_in[6];
    const int* hmap     = (const int*)d_in[7];
    const float* hist   = (const float*)d_in[8];
    const float* W1     = (const float*)d_in[9];
    const float* Wself1 = (const float*)d_in[10];
    const float* b1     = (const float*)d_in[11];
    const float* gamma  = (const float*)d_in[12];
    const float* beta   = (const float*)d_in[13];
    const float* W2     = (const float*)d_in[14];
    const float* Wself2 = (const float*)d_in[15];
    const float* b2     = (const float*)d_in[16];
    float* out = (float*)d_out;

    char* ws = (char*)d_ws;
    unsigned short* histbf = (unsigned short*)(ws);            //  7,745,536 (30256 rows)
    unsigned short* aggb   = (unsigned short*)(ws + 7745536);  //  6,144,000
    unsigned short* BF     = (unsigned short*)(ws + 13889536); //     81,920
    float* hfix            = (float*)(ws + 13971456);          //    131,072
    int* uc_node           = (int*)(ws + 14102528);            //      1,024
    int* remap             = (int*)(ws + 14103552);            //    240,000
    int* epay              = (int*)(ws + 14343552);            //  4,608,000
    int* mcount            = (int*)(ws + 18951552);            //    120,000
    int* degcnt            = (int*)(ws + 19071552);            //    384,000 (padded x16)
    float* psum            = (float*)(ws + 19455552);          //    480,256
    float* psum2           = (float*)(ws + 19935808);          //     16,384
    int* list              = (int*)(ws + 19952192);            //    131,072
    float* params          = (float*)(ws + 20083264);          //      1,024
    int* cnt               = (int*)(ws + 20084288);            //          4
    int* nuc               = (int*)(ws + 20084292);            //          4

    k_zero<<<128, 256, 0, stream>>>(hfix, mcount, degcnt, cnt, nuc);
    k_scan<<<(N1 + 255) / 256, 256, 0, stream>>>(hmap, mcount, nuc, uc_node, remap);
    k_A<<<CONV_BLKS + ESCAN_BLKS + BFRAG_BLKS, 256, 0, stream>>>(
        hist, histbf, mcount, psum, hmap, remap,
        dst1, cnt, list, src2, dst2, et2, degcnt, epay, W2, Wself2, BF);
    k_wl2<<<88, 256, 0, stream>>>(x, src1, dst1, et1, W1, Wself1, b1,
                                  cnt, list, remap, uc_node, nuc,
                                  hfix, psum, psum2);
    k_mid<<<2, 256, 0, stream>>>(psum2, hfix, nuc, gamma, beta, params, histbf);
    k_agg<<<N2, 256, 0, stream>>>((const unsigned int*)histbf, degcnt, epay,
                                  params, (unsigned int*)aggb);
    k_gemm2<<<94, 256, 0, stream>>>(aggb, histbf, remap, BF, params, b2, out);
}